// Round 1
// 553.649 us; speedup vs baseline: 1.2422x; 1.2422x over previous
//
#include <hip/hip_runtime.h>
#include <math.h>

// Problem constants (from reference): S=2048, N=32768, DIM=4, NF=30, D=2, Q=2
#define S_   2048
#define N_   32768
#define NF_  30

// jax.nn.softplus(x) = max(x,0) + log1p(exp(-|x|))
__device__ __forceinline__ float softplusf(float x) {
    return fmaxf(x, 0.0f) + log1pf(expf(-fabsf(x)));
}

// ---------------------------------------------------------------------------
// prep_kernel: blocks [0,128) -> MLP f = tanh(relu(relu(Y@W1+b1)@W2+b2)@W3+b3)
//              blocks [128,136) -> base dist + 30 radial flow steps -> Z
// ALL I/O is float32 (reference uses jnp.float32 throughout).
// Intermediates in fp32 workspace: Zws [S,4], Fws [N,2].
// ---------------------------------------------------------------------------
__global__ __launch_bounds__(256)
void prep_kernel(const float* __restrict__ eps, const float* __restrict__ mu,
                 const float* __restrict__ sigma, const float* __restrict__ x0,
                 const float* __restrict__ ap,  const float* __restrict__ bp,
                 const float* __restrict__ Y,
                 const float* __restrict__ W1, const float* __restrict__ b1,
                 const float* __restrict__ W2, const float* __restrict__ b2,
                 const float* __restrict__ W3, const float* __restrict__ b3,
                 float* __restrict__ Zws, float* __restrict__ Fws)
{
    if (blockIdx.x < 128) {
        // ---- tiny MLP, one thread per row n ----
        __shared__ float w1[100], w2[100], w3[20], B1[10], B2[10], B3[2];
        int t = threadIdx.x;
        if (t < 100)      { w1[t] = W1[t]; w2[t] = W2[t]; }
        else if (t < 120) { w3[t-100] = W3[t-100]; }
        else if (t < 130) { B1[t-120] = b1[t-120]; }
        else if (t < 140) { B2[t-130] = b2[t-130]; }
        else if (t < 142) { B3[t-140] = b3[t-140]; }
        __syncthreads();

        int n = blockIdx.x * 256 + t;   // exactly 128*256 == N_
        float y[10];
        #pragma unroll
        for (int j = 0; j < 10; j++) y[j] = Y[n*10 + j];

        float h1[10];
        #pragma unroll
        for (int i = 0; i < 10; i++) {
            float acc = B1[i];
            #pragma unroll
            for (int j = 0; j < 10; j++) acc = fmaf(y[j], w1[j*10 + i], acc);
            h1[i] = fmaxf(acc, 0.0f);
        }
        float h2[10];
        #pragma unroll
        for (int i = 0; i < 10; i++) {
            float acc = B2[i];
            #pragma unroll
            for (int j = 0; j < 10; j++) acc = fmaf(h1[j], w2[j*10 + i], acc);
            h2[i] = fmaxf(acc, 0.0f);
        }
        float f0 = B3[0], f1 = B3[1];
        #pragma unroll
        for (int j = 0; j < 10; j++) {
            f0 = fmaf(h2[j], w3[j*2 + 0], f0);
            f1 = fmaf(h2[j], w3[j*2 + 1], f1);
        }
        ((float2*)Fws)[n] = make_float2(tanhf(f0), tanhf(f1));
    } else {
        // ---- radial flow, one thread per sample s ----
        int s = (blockIdx.x - 128) * 256 + threadIdx.x;   // 8*256 == S_
        float4 ev = ((const float4*)eps)[s];
        float z[4] = {ev.x, ev.y, ev.z, ev.w};
        #pragma unroll
        for (int j = 0; j < 4; j++) {
            float m  = 3.0f * tanhf(mu[j]);
            float sg = tanhf(sigma[j]) + 1.0f;
            z[j] = fmaf(sg, z[j], m);
        }
        for (int k = 0; k < NF_; k++) {
            float a  = softplusf(ap[k]);
            float bb = softplusf(bp[k]) - a;   // beta = -alpha + softplus(b')
            float d0 = z[0] - x0[k*4 + 0];
            float d1 = z[1] - x0[k*4 + 1];
            float d2 = z[2] - x0[k*4 + 2];
            float d3 = z[3] - x0[k*4 + 3];
            float r  = sqrtf(d0*d0 + d1*d1 + d2*d2 + d3*d3);
            float bh = bb / (a + r);
            z[0] = fmaf(bh, d0, z[0]);
            z[1] = fmaf(bh, d1, z[1]);
            z[2] = fmaf(bh, d2, z[2]);
            z[3] = fmaf(bh, d3, z[3]);
        }
        ((float4*)Zws)[s] = make_float4(z[0], z[1], z[2], z[3]);
    }
}

// ---------------------------------------------------------------------------
// outer_kernel: X[s,n,q] = f[n,0]*Z[s,0,q] + f[n,1]*Z[s,1,q], fp32 out.
//
// Store-coalescing redesign: each thread owns ONE float4 = {n, n+1} x {q0,q1}
// per s, so every store instruction is lane-contiguous (64 lanes x 16 B =
// 1 KiB contiguous, every 4 lanes fill one 64 B line). Previous version
// wrote 16 B used / 32 B span per instruction with nontemporal flag ->
// partial-line writes, ~1.6 TB/s. Plain full-line stores mimic the
// fillBuffer kernel that measures 6.37 TB/s on this same buffer.
//
// grid = 64 n-chunks (512 n each) * 128 s-chunks (16 s each).
// F loaded once per thread (float4 = f[n][0],f[n][1],f[n+1][0],f[n+1][1]),
// reused across 16 s. Z staged via LDS (16 float4 per block).
// ---------------------------------------------------------------------------
#define SCH 16

__global__ __launch_bounds__(256)
void outer_kernel(const float* __restrict__ Zws, const float* __restrict__ Fws,
                  float* __restrict__ out)
{
    int nb = blockIdx.x & 63;          // 64 chunks of 512 n
    int sb = blockIdx.x >> 6;          // 128 chunks of 16 s
    int t  = threadIdx.x;

    const float4* __restrict__ F4 = (const float4*)Fws;
    float4 f = F4[nb * 256 + t];       // n0 = nb*512 + 2t: f[n0][*], f[n0+1][*]

    __shared__ float4 Zs[SCH];
    if (t < SCH)
        Zs[t] = ((const float4*)Zws)[sb * SCH + t];
    __syncthreads();

    // float4 index of out[s][n][q]: s*(N/2) + n/2 ; n/2 = nb*256 + t
    float4* dst = (float4*)out + (size_t)sb * SCH * (N_/2) + (nb * 256 + t);

    #pragma unroll
    for (int i = 0; i < SCH; i++) {
        float4 Zv = Zs[i];             // Z[s][0][0], Z[s][0][1], Z[s][1][0], Z[s][1][1]
        float4 p;
        p.x = fmaf(f.x, Zv.x, f.y * Zv.z);   // n0  , q0
        p.y = fmaf(f.x, Zv.y, f.y * Zv.w);   // n0  , q1
        p.z = fmaf(f.z, Zv.x, f.w * Zv.z);   // n0+1, q0
        p.w = fmaf(f.z, Zv.y, f.w * Zv.w);   // n0+1, q1
        dst[(size_t)i * (N_/2)] = p;
    }
}

extern "C" void kernel_launch(void* const* d_in, const int* in_sizes, int n_in,
                              void* d_out, int out_size, void* d_ws, size_t ws_size,
                              hipStream_t stream)
{
    const float* eps   = (const float*)d_in[0];
    const float* mu    = (const float*)d_in[1];
    const float* sigma = (const float*)d_in[2];
    const float* x0    = (const float*)d_in[3];
    const float* ap    = (const float*)d_in[4];
    const float* bp    = (const float*)d_in[5];
    const float* Y     = (const float*)d_in[6];
    const float* W1    = (const float*)d_in[7];
    const float* b1    = (const float*)d_in[8];
    const float* W2    = (const float*)d_in[9];
    const float* b2    = (const float*)d_in[10];
    const float* W3    = (const float*)d_in[11];
    const float* b3    = (const float*)d_in[12];

    float* Zws = (float*)d_ws;                                  // S*4 fp32 = 32 KB
    float* Fws = (float*)((char*)d_ws + S_*4*sizeof(float));    // N*2 fp32 = 256 KB

    prep_kernel<<<136, 256, 0, stream>>>(eps, mu, sigma, x0, ap, bp, Y,
                                         W1, b1, W2, b2, W3, b3, Zws, Fws);
    outer_kernel<<<(N_/512) * (S_/SCH), 256, 0, stream>>>(Zws, Fws, (float*)d_out);
}

// Round 2
// 553.183 us; speedup vs baseline: 1.2432x; 1.0008x over previous
//
#include <hip/hip_runtime.h>
#include <math.h>

// Problem constants (from reference): S=2048, N=32768, DIM=4, NF=30, D=2, Q=2
#define S_   2048
#define N_   32768
#define NF_  30

typedef float f32x4 __attribute__((ext_vector_type(4)));

// jax.nn.softplus(x) = max(x,0) + log1p(exp(-|x|))
__device__ __forceinline__ float softplusf(float x) {
    return fmaxf(x, 0.0f) + log1pf(expf(-fabsf(x)));
}

// ---------------------------------------------------------------------------
// prep_kernel: blocks [0,128) -> MLP f = tanh(relu(relu(Y@W1+b1)@W2+b2)@W3+b3)
//              blocks [128,136) -> base dist + 30 radial flow steps -> Z
// ALL I/O is float32 (reference uses jnp.float32 throughout).
// Intermediates in fp32 workspace: Zws [S,4], Fws [N,2].
// ---------------------------------------------------------------------------
__global__ __launch_bounds__(256)
void prep_kernel(const float* __restrict__ eps, const float* __restrict__ mu,
                 const float* __restrict__ sigma, const float* __restrict__ x0,
                 const float* __restrict__ ap,  const float* __restrict__ bp,
                 const float* __restrict__ Y,
                 const float* __restrict__ W1, const float* __restrict__ b1,
                 const float* __restrict__ W2, const float* __restrict__ b2,
                 const float* __restrict__ W3, const float* __restrict__ b3,
                 float* __restrict__ Zws, float* __restrict__ Fws)
{
    if (blockIdx.x < 128) {
        // ---- tiny MLP, one thread per row n ----
        __shared__ float w1[100], w2[100], w3[20], B1[10], B2[10], B3[2];
        int t = threadIdx.x;
        if (t < 100)      { w1[t] = W1[t]; w2[t] = W2[t]; }
        else if (t < 120) { w3[t-100] = W3[t-100]; }
        else if (t < 130) { B1[t-120] = b1[t-120]; }
        else if (t < 140) { B2[t-130] = b2[t-130]; }
        else if (t < 142) { B3[t-140] = b3[t-140]; }
        __syncthreads();

        int n = blockIdx.x * 256 + t;   // exactly 128*256 == N_
        float y[10];
        #pragma unroll
        for (int j = 0; j < 10; j++) y[j] = Y[n*10 + j];

        float h1[10];
        #pragma unroll
        for (int i = 0; i < 10; i++) {
            float acc = B1[i];
            #pragma unroll
            for (int j = 0; j < 10; j++) acc = fmaf(y[j], w1[j*10 + i], acc);
            h1[i] = fmaxf(acc, 0.0f);
        }
        float h2[10];
        #pragma unroll
        for (int i = 0; i < 10; i++) {
            float acc = B2[i];
            #pragma unroll
            for (int j = 0; j < 10; j++) acc = fmaf(h1[j], w2[j*10 + i], acc);
            h2[i] = fmaxf(acc, 0.0f);
        }
        float f0 = B3[0], f1 = B3[1];
        #pragma unroll
        for (int j = 0; j < 10; j++) {
            f0 = fmaf(h2[j], w3[j*2 + 0], f0);
            f1 = fmaf(h2[j], w3[j*2 + 1], f1);
        }
        ((float2*)Fws)[n] = make_float2(tanhf(f0), tanhf(f1));
    } else {
        // ---- radial flow, one thread per sample s ----
        int s = (blockIdx.x - 128) * 256 + threadIdx.x;   // 8*256 == S_
        float4 ev = ((const float4*)eps)[s];
        float z[4] = {ev.x, ev.y, ev.z, ev.w};
        #pragma unroll
        for (int j = 0; j < 4; j++) {
            float m  = 3.0f * tanhf(mu[j]);
            float sg = tanhf(sigma[j]) + 1.0f;
            z[j] = fmaf(sg, z[j], m);
        }
        for (int k = 0; k < NF_; k++) {
            float a  = softplusf(ap[k]);
            float bb = softplusf(bp[k]) - a;   // beta = -alpha + softplus(b')
            float d0 = z[0] - x0[k*4 + 0];
            float d1 = z[1] - x0[k*4 + 1];
            float d2 = z[2] - x0[k*4 + 2];
            float d3 = z[3] - x0[k*4 + 3];
            float r  = sqrtf(d0*d0 + d1*d1 + d2*d2 + d3*d3);
            float bh = bb / (a + r);
            z[0] = fmaf(bh, d0, z[0]);
            z[1] = fmaf(bh, d1, z[1]);
            z[2] = fmaf(bh, d2, z[2]);
            z[3] = fmaf(bh, d3, z[3]);
        }
        ((float4*)Zws)[s] = make_float4(z[0], z[1], z[2], z[3]);
    }
}

// ---------------------------------------------------------------------------
// outer_kernel: X[s,n,q] = f[n,0]*Z[s,0,q] + f[n,1]*Z[s,1,q], fp32 out.
//
// R1 established the contiguous-store layout (each wave store = 1 KiB
// contiguous, full 128 B line coverage): outer ~197 us = 2.7 TB/s.
// R2 change: nontemporal stores on top of the contiguous layout, to
// bypass L2 write-allocate / RFO like the rocclr fill (6.37 TB/s,
// FETCH_SIZE ~0) does. Everything else identical to R1 for clean A/B.
//
// grid = 64 n-chunks (512 n each) * 128 s-chunks (16 s each).
// ---------------------------------------------------------------------------
#define SCH 16

__global__ __launch_bounds__(256)
void outer_kernel(const float* __restrict__ Zws, const float* __restrict__ Fws,
                  float* __restrict__ out)
{
    int nb = blockIdx.x & 63;          // 64 chunks of 512 n
    int sb = blockIdx.x >> 6;          // 128 chunks of 16 s
    int t  = threadIdx.x;

    const float4* __restrict__ F4 = (const float4*)Fws;
    float4 f = F4[nb * 256 + t];       // n0 = nb*512 + 2t: f[n0][*], f[n0+1][*]

    __shared__ float4 Zs[SCH];
    if (t < SCH)
        Zs[t] = ((const float4*)Zws)[sb * SCH + t];
    __syncthreads();

    // float4 index of out[s][n][q]: s*(N/2) + n/2 ; n/2 = nb*256 + t
    f32x4* dst = (f32x4*)out + (size_t)sb * SCH * (N_/2) + (nb * 256 + t);

    #pragma unroll
    for (int i = 0; i < SCH; i++) {
        float4 Zv = Zs[i];             // Z[s][0][0], Z[s][0][1], Z[s][1][0], Z[s][1][1]
        f32x4 p;
        p.x = fmaf(f.x, Zv.x, f.y * Zv.z);   // n0  , q0
        p.y = fmaf(f.x, Zv.y, f.y * Zv.w);   // n0  , q1
        p.z = fmaf(f.z, Zv.x, f.w * Zv.z);   // n0+1, q0
        p.w = fmaf(f.z, Zv.y, f.w * Zv.w);   // n0+1, q1
        __builtin_nontemporal_store(p, dst + (size_t)i * (N_/2));
    }
}

extern "C" void kernel_launch(void* const* d_in, const int* in_sizes, int n_in,
                              void* d_out, int out_size, void* d_ws, size_t ws_size,
                              hipStream_t stream)
{
    const float* eps   = (const float*)d_in[0];
    const float* mu    = (const float*)d_in[1];
    const float* sigma = (const float*)d_in[2];
    const float* x0    = (const float*)d_in[3];
    const float* ap    = (const float*)d_in[4];
    const float* bp    = (const float*)d_in[5];
    const float* Y     = (const float*)d_in[6];
    const float* W1    = (const float*)d_in[7];
    const float* b1    = (const float*)d_in[8];
    const float* W2    = (const float*)d_in[9];
    const float* b2    = (const float*)d_in[10];
    const float* W3    = (const float*)d_in[11];
    const float* b3    = (const float*)d_in[12];

    float* Zws = (float*)d_ws;                                  // S*4 fp32 = 32 KB
    float* Fws = (float*)((char*)d_ws + S_*4*sizeof(float));    // N*2 fp32 = 256 KB

    prep_kernel<<<136, 256, 0, stream>>>(eps, mu, sigma, x0, ap, bp, Y,
                                         W1, b1, W2, b2, W3, b3, Zws, Fws);
    outer_kernel<<<(N_/512) * (S_/SCH), 256, 0, stream>>>(Zws, Fws, (float*)d_out);
}